// Round 1
// baseline (1833.730 us; speedup 1.0000x reference)
//
#include <hip/hip_runtime.h>
#include <cstddef>

typedef __bf16 bf16;
typedef bf16 bf16x8 __attribute__((ext_vector_type(8)));
typedef float f32x4 __attribute__((ext_vector_type(4)));

#define NLAYER 6
#define HIDD 512
#define SEQL 768
#define NBATCH 16
#define MROWS (NBATCH * SEQL) /* 12288 */

__device__ __forceinline__ void gll16(const void* g, void* l) {
  __builtin_amdgcn_global_load_lds((const __attribute__((address_space(1))) void*)g,
                                   (__attribute__((address_space(3))) void*)l, 16, 0, 0);
}

__device__ __forceinline__ float gelu_f(float v) {
  return 0.5f * v * (1.0f + erff(v * 0.7071067811865475f));
}

// ---------------- weight transpose+convert: (L,K,N) f32 -> (L,N,K) bf16 ----------------
__global__ __launch_bounds__(256) void wtrans(const float* __restrict__ in,
                                              bf16* __restrict__ out, int K, int N) {
  __shared__ float tile[32 * 33];
  const int l = blockIdx.z;
  const float* inp = in + (size_t)l * K * N;
  bf16* outp = out + (size_t)l * K * N;
  const int kb = blockIdx.y * 32, nb = blockIdx.x * 32;
  const int t = threadIdx.x;
#pragma unroll
  for (int i = 0; i < 4; ++i) {
    int lin = i * 256 + t, r = lin >> 5, c = lin & 31;
    tile[r * 33 + c] = inp[(size_t)(kb + r) * N + nb + c];
  }
  __syncthreads();
#pragma unroll
  for (int i = 0; i < 4; ++i) {
    int lin = i * 256 + t, r = lin >> 5, c = lin & 31;
    outp[(size_t)(nb + r) * K + kb + c] = (bf16)tile[c * 33 + r];
  }
}

// ---------------- embedding + shift + timing signal ----------------
__global__ __launch_bounds__(128) void embed_kernel(const float* __restrict__ X,
                                                    const float* __restrict__ ET,
                                                    float* __restrict__ Hf,
                                                    bf16* __restrict__ Hb) {
  const int bs = blockIdx.x;  // b*768 + s
  const int s = bs % SEQL;
  const int b = bs / SEQL;
  const int t = threadIdx.x;
  const int r = s / 48, c = s % 48;
  float vals[4] = {0.f, 0.f, 0.f, 0.f};
  const int ssrc = s - 1;
  if (ssrc >= 0) {
    const int rs = ssrc / 48, c48 = ssrc % 48;
    const int col = c48 / 3, ch = c48 % 3;
    const float x = X[((b * 3 + ch) * 16 + rs) * 16 + col];
    const int idx = (int)(x * 255.0f) + ch * 256;
    const float sq = 22.62741699796952f;  // sqrt(512)
#pragma unroll
    for (int i = 0; i < 4; ++i) vals[i] = ET[(size_t)idx * HIDD + t + 128 * i] * sq;
  }
  const float Cc = -0.07252236513366286f;  // -ln(10000)/127
#pragma unroll
  for (int i = 0; i < 4; ++i) {
    const int d = t + 128 * i;
    float ts;
    if (d < 128)      ts = sinf((float)r * expf((float)d * Cc));
    else if (d < 256) ts = cosf((float)r * expf((float)(d - 128) * Cc));
    else if (d < 384) ts = sinf((float)c * expf((float)(d - 256) * Cc));
    else              ts = cosf((float)c * expf((float)(d - 384) * Cc));
    const float v = vals[i] + ts;
    Hf[(size_t)bs * HIDD + d] = v;
    Hb[(size_t)bs * HIDD + d] = (bf16)v;
  }
}

// ---------------- generic bf16 GEMM, Bt is (N,K) row-major ----------------
// EPI 0: store bf16 | 1: +bias, gelu, bf16 | 2: +bias,+resid, f32 | 3: +resid, f32
template <int EPI>
__global__ __launch_bounds__(256) void gemm_bt(const bf16* __restrict__ A,
                                               const bf16* __restrict__ Bt,
                                               void* __restrict__ Cv,
                                               const float* __restrict__ bias,
                                               const float* __restrict__ resid,
                                               int N, int K) {
  __shared__ bf16 As[128 * 32];
  __shared__ bf16 Bs[128 * 32];
  const int tid = threadIdx.x;
  const int lane = tid & 63, w = tid >> 6;
  const int wr = w >> 1, wc = w & 1;
  const int l15 = lane & 15, g = lane >> 4;
  const int m0 = blockIdx.y * 128, n0 = blockIdx.x * 128;
  f32x4 acc[4][4] = {};
  const int rr = tid >> 2, kc = tid & 3;
  const bf16* Ap0 = A + (size_t)(m0 + rr) * K + kc * 8;
  const bf16* Ap1 = A + (size_t)(m0 + 64 + rr) * K + kc * 8;
  const bf16* Bp0 = Bt + (size_t)(n0 + rr) * K + kc * 8;
  const bf16* Bp1 = Bt + (size_t)(n0 + 64 + rr) * K + kc * 8;
  bf16* As0 = As + tid * 8;
  bf16* As1 = As + 2048 + tid * 8;
  bf16* Bs0 = Bs + tid * 8;
  bf16* Bs1 = Bs + 2048 + tid * 8;

  for (int kt = 0; kt < K; kt += 32) {
    gll16(Ap0 + kt, As0);
    gll16(Ap1 + kt, As1);
    gll16(Bp0 + kt, Bs0);
    gll16(Bp1 + kt, Bs1);
    __syncthreads();
    bf16x8 af[4], bv[4];
#pragma unroll
    for (int i = 0; i < 4; ++i)
      af[i] = *(const bf16x8*)&As[(wr * 64 + i * 16 + l15) * 32 + 8 * g];
#pragma unroll
    for (int i = 0; i < 4; ++i)
      bv[i] = *(const bf16x8*)&Bs[(wc * 64 + i * 16 + l15) * 32 + 8 * g];
#pragma unroll
    for (int mi = 0; mi < 4; ++mi)
#pragma unroll
      for (int ni = 0; ni < 4; ++ni)
        acc[mi][ni] = __builtin_amdgcn_mfma_f32_16x16x32_bf16(af[mi], bv[ni], acc[mi][ni], 0, 0, 0);
    __syncthreads();
  }
  // epilogue: D row = (lane>>4)*4 + reg, col = lane&15
#pragma unroll
  for (int mi = 0; mi < 4; ++mi) {
#pragma unroll
    for (int ni = 0; ni < 4; ++ni) {
      const int row = m0 + wr * 64 + mi * 16 + 4 * g;
      const int col = n0 + wc * 64 + ni * 16 + l15;
      float bvv = 0.f;
      if constexpr (EPI == 1 || EPI == 2) bvv = bias[col];
#pragma unroll
      for (int r = 0; r < 4; ++r) {
        float v = acc[mi][ni][r];
        if constexpr (EPI == 1 || EPI == 2) v += bvv;
        if constexpr (EPI == 2 || EPI == 3) v += resid[(size_t)(row + r) * N + col];
        if constexpr (EPI == 1) v = gelu_f(v);
        if constexpr (EPI == 0 || EPI == 1)
          ((bf16*)Cv)[(size_t)(row + r) * N + col] = (bf16)v;
        else
          ((float*)Cv)[(size_t)(row + r) * N + col] = v;
      }
    }
  }
}

// ---------------- V transpose: (B,S,H,dh) -> (B,H,dh,S) ----------------
__global__ __launch_bounds__(256) void vtrans(const bf16* __restrict__ V,
                                              bf16* __restrict__ Vt) {
  const int st = blockIdx.x, h = blockIdx.y, b = blockIdx.z;
  __shared__ bf16 tile[64 * 68];
  const int t = threadIdx.x;
#pragma unroll
  for (int i = 0; i < 16; ++i) {
    int lin = i * 256 + t, s = lin >> 6, d = lin & 63;
    tile[s * 68 + d] = V[(size_t)(b * SEQL + st * 64 + s) * HIDD + h * 64 + d];
  }
  __syncthreads();
#pragma unroll
  for (int i = 0; i < 16; ++i) {
    int lin = i * 256 + t, d = lin >> 6, s = lin & 63;
    Vt[(size_t)((b * 8 + h) * 64 + d) * SEQL + st * 64 + s] = tile[s * 68 + d];
  }
}

// ---------------- local attention ----------------
template <bool FIRST>
__global__ __launch_bounds__(512) void attn_kernel(const bf16* __restrict__ Q,
                                                   const bf16* __restrict__ Km,
                                                   const bf16* __restrict__ Vt,
                                                   bf16* __restrict__ O) {
  constexpr int NF = FIRST ? 8 : 16;   // key fragments of 16
  constexpr int KC = FIRST ? 4 : 8;    // key chunks of 32
  const int n = FIRST ? 0 : (blockIdx.x + 1);
  const int h = blockIdx.y, b = blockIdx.z;
  const int tid = threadIdx.x, w = tid >> 6, lane = tid & 63;
  const int l15 = lane & 15, g = lane >> 4;
  __shared__ bf16 P[8][16][256];  // 64 KB
  const int keybase = FIRST ? 0 : (n - 1) * 128;
  const int qbase = n * 128;
  const bf16* qrow = Q + (size_t)(b * SEQL + qbase + w * 16 + l15) * HIDD + h * 64;
  bf16x8 qf0 = *(const bf16x8*)(qrow + 8 * g);
  bf16x8 qf1 = *(const bf16x8*)(qrow + 32 + 8 * g);
  f32x4 S[NF];
#pragma unroll
  for (int nf = 0; nf < NF; ++nf) S[nf] = f32x4{0.f, 0.f, 0.f, 0.f};
#pragma unroll
  for (int nf = 0; nf < NF; ++nf) {
    const bf16* krow = Km + (size_t)(b * SEQL + keybase + nf * 16 + l15) * HIDD + h * 64;
    bf16x8 kf0 = *(const bf16x8*)(krow + 8 * g);
    bf16x8 kf1 = *(const bf16x8*)(krow + 32 + 8 * g);
    S[nf] = __builtin_amdgcn_mfma_f32_16x16x32_bf16(qf0, kf0, S[nf], 0, 0, 0);
    S[nf] = __builtin_amdgcn_mfma_f32_16x16x32_bf16(qf1, kf1, S[nf], 0, 0, 0);
  }
  // scale + mask + softmax; row q = w*16 + 4*g + rr lives in the 16 lanes of group g
#pragma unroll
  for (int rr = 0; rr < 4; ++rr) {
    const int qloc = w * 16 + 4 * g + rr;
    float mx = -3.0e38f;
#pragma unroll
    for (int nf = 0; nf < NF; ++nf) {
      const int key = nf * 16 + l15;
      const bool valid = FIRST ? (key <= qloc) : (key <= qloc + 128);
      float v = valid ? S[nf][rr] * 0.125f : -1.0e9f;
      S[nf][rr] = v;
      mx = fmaxf(mx, v);
    }
    mx = fmaxf(mx, __shfl_xor(mx, 1));
    mx = fmaxf(mx, __shfl_xor(mx, 2));
    mx = fmaxf(mx, __shfl_xor(mx, 4));
    mx = fmaxf(mx, __shfl_xor(mx, 8));
    float sden = 0.f;
#pragma unroll
    for (int nf = 0; nf < NF; ++nf) {
      float e = expf(S[nf][rr] - mx);
      S[nf][rr] = e;
      sden += e;
    }
    sden += __shfl_xor(sden, 1);
    sden += __shfl_xor(sden, 2);
    sden += __shfl_xor(sden, 4);
    sden += __shfl_xor(sden, 8);
    const float rcp = 1.0f / sden;
#pragma unroll
    for (int nf = 0; nf < NF; ++nf)
      P[w][4 * g + rr][nf * 16 + l15] = (bf16)(S[nf][rr] * rcp);
  }
  // PV: O[q][d] = P @ V ; A-frag from LDS (same-wave write->read, in-order)
  f32x4 Oacc[4];
#pragma unroll
  for (int i = 0; i < 4; ++i) Oacc[i] = f32x4{0.f, 0.f, 0.f, 0.f};
#pragma unroll
  for (int kc = 0; kc < KC; ++kc) {
    bf16x8 pa = *(const bf16x8*)&P[w][l15][kc * 32 + 8 * g];
#pragma unroll
    for (int nf = 0; nf < 4; ++nf) {
      const bf16* vrow = Vt + (size_t)((b * 8 + h) * 64 + nf * 16 + l15) * SEQL +
                         keybase + kc * 32 + 8 * g;
      bf16x8 vf = *(const bf16x8*)vrow;
      Oacc[nf] = __builtin_amdgcn_mfma_f32_16x16x32_bf16(pa, vf, Oacc[nf], 0, 0, 0);
    }
  }
#pragma unroll
  for (int nf = 0; nf < 4; ++nf)
#pragma unroll
    for (int rr = 0; rr < 4; ++rr)
      O[(size_t)(b * SEQL + qbase + w * 16 + 4 * g + rr) * HIDD + h * 64 + nf * 16 + l15] =
          (bf16)Oacc[nf][rr];
}

// ---------------- LayerNorm over 512, writes f32 + bf16 ----------------
__global__ __launch_bounds__(256) void ln_kernel(const float* __restrict__ Z,
                                                 const float* __restrict__ Gm,
                                                 const float* __restrict__ Bv,
                                                 float* __restrict__ Hf,
                                                 bf16* __restrict__ Hb) {
  const int row = blockIdx.x * 4 + (threadIdx.x >> 6);
  const int lane = threadIdx.x & 63;
  const float* zr = Z + (size_t)row * HIDD + lane * 8;
  f32x4 v0 = *(const f32x4*)zr;
  f32x4 v1 = *(const f32x4*)(zr + 4);
  float s = v0[0] + v0[1] + v0[2] + v0[3] + v1[0] + v1[1] + v1[2] + v1[3];
#pragma unroll
  for (int m = 1; m < 64; m <<= 1) s += __shfl_xor(s, m);
  const float mean = s * (1.0f / 512.0f);
  float q = 0.f;
#pragma unroll
  for (int j = 0; j < 4; ++j) {
    float d0 = v0[j] - mean, d1 = v1[j] - mean;
    q += d0 * d0 + d1 * d1;
  }
#pragma unroll
  for (int m = 1; m < 64; m <<= 1) q += __shfl_xor(q, m);
  const float rs = rsqrtf(q * (1.0f / 512.0f) + 1e-6f);
  const int dbase = lane * 8;
  f32x4 g0 = *(const f32x4*)(Gm + dbase), g1 = *(const f32x4*)(Gm + dbase + 4);
  f32x4 b0 = *(const f32x4*)(Bv + dbase), b1 = *(const f32x4*)(Bv + dbase + 4);
  f32x4 o0, o1;
  bf16x8 ob;
#pragma unroll
  for (int j = 0; j < 4; ++j) {
    o0[j] = (v0[j] - mean) * rs * g0[j] + b0[j];
    o1[j] = (v1[j] - mean) * rs * g1[j] + b1[j];
    ob[j] = (bf16)o0[j];
    ob[j + 4] = (bf16)o1[j];
  }
  *(f32x4*)(Hf + (size_t)row * HIDD + dbase) = o0;
  *(f32x4*)(Hf + (size_t)row * HIDD + dbase + 4) = o1;
  *(bf16x8*)(Hb + (size_t)row * HIDD + dbase) = ob;
}

// ---------------- final projection: partials over K-chunks of 512 ----------------
__global__ __launch_bounds__(256) void proj_partial(const float* __restrict__ Hf,
                                                    const float* __restrict__ W,
                                                    float* __restrict__ part) {
  const int kc = blockIdx.x;  // 0..767
  const int t = threadIdx.x;
  __shared__ float Al[512 * 20];
  const size_t k0 = (size_t)kc * 512;
#pragma unroll
  for (int i = 0; i < 32; ++i) {
    int lin = i * 256 + t, m = lin >> 9, kk = lin & 511;
    Al[kk * 20 + m] = Hf[(size_t)m * 393216 + k0 + kk];
  }
  __syncthreads();
  float acc[16] = {};
  for (int kk = 0; kk < 512; ++kk) {
    const float wv = W[(k0 + kk) * 256 + t];
    const f32x4* a = (const f32x4*)&Al[kk * 20];
#pragma unroll
    for (int j = 0; j < 4; ++j) {
      f32x4 av = a[j];
      acc[j * 4 + 0] += av[0] * wv;
      acc[j * 4 + 1] += av[1] * wv;
      acc[j * 4 + 2] += av[2] * wv;
      acc[j * 4 + 3] += av[3] * wv;
    }
  }
#pragma unroll
  for (int m = 0; m < 16; ++m) part[(size_t)kc * 4096 + m * 256 + t] = acc[m];
}

__global__ __launch_bounds__(256) void proj_reduce1(const float* __restrict__ part,
                                                    float* __restrict__ part2) {
  const int i = blockIdx.x * 256 + threadIdx.x;
  const int cb = blockIdx.y;
  float s = 0.f;
  for (int c = cb * 64; c < cb * 64 + 64; ++c) s += part[(size_t)c * 4096 + i];
  part2[(size_t)cb * 4096 + i] = s;
}

__global__ __launch_bounds__(256) void proj_final(const float* __restrict__ part2,
                                                  const float* __restrict__ g,
                                                  const float* __restrict__ bt,
                                                  float* __restrict__ out) {
  const int row = blockIdx.x, t = threadIdx.x;
  float v = 0.f;
#pragma unroll
  for (int c = 0; c < 12; ++c) v += part2[(size_t)c * 4096 + row * 256 + t];
  const float x = gelu_f(v);
  __shared__ float red[256];
  red[t] = x;
  __syncthreads();
  for (int off = 128; off > 0; off >>= 1) {
    if (t < off) red[t] += red[t + off];
    __syncthreads();
  }
  const float mean = red[0] * (1.0f / 256.0f);
  __syncthreads();
  const float dx = x - mean;
  red[t] = dx * dx;
  __syncthreads();
  for (int off = 128; off > 0; off >>= 1) {
    if (t < off) red[t] += red[t + off];
    __syncthreads();
  }
  const float var = red[0] * (1.0f / 256.0f);
  const float rs = rsqrtf(var + 1e-6f);
  out[row * 256 + t] = dx * rs * g[t] + bt[t];
}

extern "C" void kernel_launch(void* const* d_in, const int* in_sizes, int n_in,
                              void* d_out, int out_size, void* d_ws, size_t ws_size,
                              hipStream_t stream) {
  const float* X = (const float*)d_in[0];
  const float* ET = (const float*)d_in[1];
  const float* Wq = (const float*)d_in[2];
  const float* Wk = (const float*)d_in[3];
  const float* Wv = (const float*)d_in[4];
  const float* Wo = (const float*)d_in[5];
  const float* ln1g = (const float*)d_in[6];
  const float* ln1b = (const float*)d_in[7];
  const float* W1 = (const float*)d_in[8];
  const float* b1 = (const float*)d_in[9];
  const float* W2 = (const float*)d_in[10];
  const float* b2 = (const float*)d_in[11];
  const float* ln2g = (const float*)d_in[12];
  const float* ln2b = (const float*)d_in[13];
  const float* PW = (const float*)d_in[14];
  const float* og = (const float*)d_in[15];
  const float* obv = (const float*)d_in[16];
  float* out = (float*)d_out;

  char* p = (char*)d_ws;
  auto alloc = [&](size_t bytes) {
    char* r = p;
    p += (bytes + 255) & ~(size_t)255;
    return r;
  };
  bf16* Wqt = (bf16*)alloc((size_t)NLAYER * 512 * 512 * 2);
  bf16* Wkt = (bf16*)alloc((size_t)NLAYER * 512 * 512 * 2);
  bf16* Wvt = (bf16*)alloc((size_t)NLAYER * 512 * 512 * 2);
  bf16* Wot = (bf16*)alloc((size_t)NLAYER * 512 * 512 * 2);
  bf16* W1t = (bf16*)alloc((size_t)NLAYER * 512 * 2048 * 2);
  bf16* W2t = (bf16*)alloc((size_t)NLAYER * 512 * 2048 * 2);
  float* hF = (float*)alloc((size_t)MROWS * HIDD * 4);
  bf16* hB = (bf16*)alloc((size_t)MROWS * HIDD * 2);
  float* zF = (float*)alloc((size_t)MROWS * HIDD * 4);
  bf16* qB = (bf16*)alloc((size_t)MROWS * HIDD * 2);
  bf16* kB = (bf16*)alloc((size_t)MROWS * HIDD * 2);
  bf16* vB = (bf16*)alloc((size_t)MROWS * HIDD * 2);
  bf16* vT = (bf16*)alloc((size_t)MROWS * HIDD * 2);
  bf16* aO = (bf16*)alloc((size_t)MROWS * HIDD * 2);
  bf16* mid = (bf16*)alloc((size_t)MROWS * 2048 * 2);
  float* part = (float*)alloc((size_t)768 * 4096 * 4);
  float* part2 = (float*)alloc((size_t)12 * 4096 * 4);
  (void)ws_size; (void)n_in; (void)in_sizes; (void)out_size;

  // weight conversion (per call; cheap)
  wtrans<<<dim3(16, 16, 6), 256, 0, stream>>>(Wq, Wqt, 512, 512);
  wtrans<<<dim3(16, 16, 6), 256, 0, stream>>>(Wk, Wkt, 512, 512);
  wtrans<<<dim3(16, 16, 6), 256, 0, stream>>>(Wv, Wvt, 512, 512);
  wtrans<<<dim3(16, 16, 6), 256, 0, stream>>>(Wo, Wot, 512, 512);
  wtrans<<<dim3(64, 16, 6), 256, 0, stream>>>(W1, W1t, 512, 2048);
  wtrans<<<dim3(16, 64, 6), 256, 0, stream>>>(W2, W2t, 2048, 512);

  embed_kernel<<<MROWS, 128, 0, stream>>>(X, ET, hF, hB);

  for (int i = 0; i < NLAYER; ++i) {
    const size_t wo512 = (size_t)i * 512 * 512;
    const size_t wo2048 = (size_t)i * 512 * 2048;
    gemm_bt<0><<<dim3(4, 96), 256, 0, stream>>>(hB, Wqt + wo512, qB, nullptr, nullptr, 512, 512);
    gemm_bt<0><<<dim3(4, 96), 256, 0, stream>>>(hB, Wkt + wo512, kB, nullptr, nullptr, 512, 512);
    gemm_bt<0><<<dim3(4, 96), 256, 0, stream>>>(hB, Wvt + wo512, vB, nullptr, nullptr, 512, 512);
    vtrans<<<dim3(12, 8, 16), 256, 0, stream>>>(vB, vT);
    attn_kernel<true><<<dim3(1, 8, 16), 512, 0, stream>>>(qB, kB, vT, aO);
    attn_kernel<false><<<dim3(5, 8, 16), 512, 0, stream>>>(qB, kB, vT, aO);
    gemm_bt<3><<<dim3(4, 96), 256, 0, stream>>>(aO, Wot + wo512, zF, nullptr, hF, 512, 512);
    ln_kernel<<<MROWS / 4, 256, 0, stream>>>(zF, ln1g + i * 512, ln1b + i * 512, hF, hB);
    gemm_bt<1><<<dim3(16, 96), 256, 0, stream>>>(hB, W1t + wo2048, mid, b1 + i * 2048, nullptr, 2048, 512);
    gemm_bt<2><<<dim3(4, 96), 256, 0, stream>>>(mid, W2t + wo2048, zF, b2 + i * 512, hF, 512, 2048);
    ln_kernel<<<MROWS / 4, 256, 0, stream>>>(zF, ln2g + i * 512, ln2b + i * 512, hF, hB);
  }

  proj_partial<<<768, 256, 0, stream>>>(hF, PW, part);
  proj_reduce1<<<dim3(16, 12), 256, 0, stream>>>(part, part2);
  proj_final<<<16, 256, 0, stream>>>(part2, og, obv, out);
}

// Round 2
// 1767.540 us; speedup vs baseline: 1.0374x; 1.0374x over previous
//
#include <hip/hip_runtime.h>
#include <cstddef>

typedef __bf16 bf16;
typedef bf16 bf16x8 __attribute__((ext_vector_type(8)));
typedef float f32x4 __attribute__((ext_vector_type(4)));

#define NLAYER 6
#define HIDD 512
#define SEQL 768
#define NBATCH 16
#define MROWS (NBATCH * SEQL) /* 12288 */
#define QKVS 1536

__device__ __forceinline__ void gll16(const void* g, void* l) {
  __builtin_amdgcn_global_load_lds((const __attribute__((address_space(1))) void*)g,
                                   (__attribute__((address_space(3))) void*)l, 16, 0, 0);
}

__device__ __forceinline__ float gelu_f(float v) {
  return 0.5f * v * (1.0f + erff(v * 0.7071067811865475f));
}

// ---------------- weight transpose+convert: (L,K,N) f32 -> (L,N,K) bf16 ----------------
__global__ __launch_bounds__(256) void wtrans(const float* __restrict__ in,
                                              bf16* __restrict__ out, int K, int N,
                                              size_t lstride_out) {
  __shared__ float tile[32 * 33];
  const int l = blockIdx.z;
  const float* inp = in + (size_t)l * K * N;
  bf16* outp = out + (size_t)l * lstride_out;
  const int kb = blockIdx.y * 32, nb = blockIdx.x * 32;
  const int t = threadIdx.x;
#pragma unroll
  for (int i = 0; i < 4; ++i) {
    int lin = i * 256 + t, r = lin >> 5, c = lin & 31;
    tile[r * 33 + c] = inp[(size_t)(kb + r) * N + nb + c];
  }
  __syncthreads();
#pragma unroll
  for (int i = 0; i < 4; ++i) {
    int lin = i * 256 + t, r = lin >> 5, c = lin & 31;
    outp[(size_t)(nb + r) * K + kb + c] = (bf16)tile[c * 33 + r];
  }
}

// ---------------- embedding + shift + timing signal ----------------
__global__ __launch_bounds__(128) void embed_kernel(const float* __restrict__ X,
                                                    const float* __restrict__ ET,
                                                    float* __restrict__ Hf,
                                                    bf16* __restrict__ Hb) {
  const int bs = blockIdx.x;  // b*768 + s
  const int s = bs % SEQL;
  const int b = bs / SEQL;
  const int t = threadIdx.x;
  const int r = s / 48, c = s % 48;
  float vals[4] = {0.f, 0.f, 0.f, 0.f};
  const int ssrc = s - 1;
  if (ssrc >= 0) {
    const int rs = ssrc / 48, c48 = ssrc % 48;
    const int col = c48 / 3, ch = c48 % 3;
    const float x = X[((b * 3 + ch) * 16 + rs) * 16 + col];
    const int idx = (int)(x * 255.0f) + ch * 256;
    const float sq = 22.62741699796952f;  // sqrt(512)
#pragma unroll
    for (int i = 0; i < 4; ++i) vals[i] = ET[(size_t)idx * HIDD + t + 128 * i] * sq;
  }
  const float Cc = -0.07252236513366286f;  // -ln(10000)/127
#pragma unroll
  for (int i = 0; i < 4; ++i) {
    const int d = t + 128 * i;
    float ts;
    if (d < 128)      ts = sinf((float)r * expf((float)d * Cc));
    else if (d < 256) ts = cosf((float)r * expf((float)(d - 128) * Cc));
    else if (d < 384) ts = sinf((float)c * expf((float)(d - 256) * Cc));
    else              ts = cosf((float)c * expf((float)(d - 384) * Cc));
    const float v = vals[i] + ts;
    Hf[(size_t)bs * HIDD + d] = v;
    Hb[(size_t)bs * HIDD + d] = (bf16)v;
  }
}

// =========================================================================
// 256x256 8-phase GEMM (T2 swizzle + T3/T4 counted vmcnt + T5 setprio).
// A: (M,K) bf16 row-major; Bt: (N,K) bf16 row-major; K % 128 == 0, K >= 256.
// 8 waves (2M x 4N), per-wave 128x64 output, BK=64, dbuf LDS = 128 KiB dyn.
// LDS halves: A-half h = rows {r : (r>>6)&1 == h}; B-half h = {n : (n>>5)&1==h}
// granule swizzle: byte = lr*128 + ((c ^ (lr&7))*16)  [both-sides, rule #21]
// EPI 0: store bf16 | 1: +bias, gelu, store bf16
// =========================================================================
template <int MH, int NH>
__device__ __forceinline__ void mfma_quad(f32x4 (&acc)[8][4], const bf16x8 (&ar)[4][2],
                                          const bf16x8 (&br)[2][2]) {
#pragma unroll
  for (int mi = 0; mi < 4; ++mi)
#pragma unroll
    for (int ni = 0; ni < 2; ++ni) {
      f32x4 cc = acc[MH * 4 + mi][NH * 2 + ni];
      cc = __builtin_amdgcn_mfma_f32_16x16x32_bf16(ar[mi][0], br[ni][0], cc, 0, 0, 0);
      cc = __builtin_amdgcn_mfma_f32_16x16x32_bf16(ar[mi][1], br[ni][1], cc, 0, 0, 0);
      acc[MH * 4 + mi][NH * 2 + ni] = cc;
    }
}

#define BAR1                                              \
  __builtin_amdgcn_s_barrier();                           \
  asm volatile("s_waitcnt lgkmcnt(0)" ::: "memory");      \
  __builtin_amdgcn_sched_barrier(0);                      \
  __builtin_amdgcn_s_setprio(1);
#define BAR2                                              \
  __builtin_amdgcn_s_setprio(0);                          \
  __builtin_amdgcn_s_barrier();
#define VMC4 asm volatile("s_waitcnt vmcnt(4)" ::: "memory");
#define VMC0 asm volatile("s_waitcnt vmcnt(0)" ::: "memory");

template <int EPI>
__global__ __launch_bounds__(512, 2) void gemm8p(const bf16* __restrict__ A,
                                                 const bf16* __restrict__ Bt,
                                                 bf16* __restrict__ C,
                                                 const float* __restrict__ bias,
                                                 int N, int K) {
  extern __shared__ char sm[];
  const int tid = threadIdx.x;
  const int w = tid >> 6, lane = tid & 63;
  const int l15 = lane & 15, g = lane >> 4;
  const int wm = w >> 2, wn = w & 3;
  const int m0 = blockIdx.y * 256, n0 = blockIdx.x * 256;
  const int NT = K >> 6;

  // ---- staging (writer) constants ----
  const int lr0 = w * 8 + (lane >> 3);                    // j=0 local row
  const int csw = (lane & 7) ^ ((lane >> 3) & 7);         // swizzled granule col
  const int nB0 = (lr0 >> 5) * 64 + (lr0 & 31);
  const bf16* Ag = A + (size_t)m0 * K + csw * 8;
  const bf16* Bg = Bt + (size_t)n0 * K + csw * 8;
  char* smt = sm + w * 1024 + lane * 16;

  auto STA = [&](int h, int t) {
    char* l0 = smt + ((t & 1) * 4 + h) * 16384;
    const bf16* g0 = Ag + (size_t)(h * 64 + lr0) * K + t * 64;
    gll16(g0, l0);
    gll16(g0 + (size_t)128 * K, l0 + 8192);
  };
  auto STB = [&](int h, int t) {
    char* l0 = smt + ((t & 1) * 4 + 2 + h) * 16384;
    const bf16* g0 = Bg + (size_t)(h * 32 + nB0) * K + t * 64;
    gll16(g0, l0);
    gll16(g0 + (size_t)128 * K, l0 + 8192);
  };

  // ---- reader constants ----
  bf16x8 ar[4][2], br[2][2];
  const int rdA = (wm * 64 + l15) * 128;
  const int rdB = (wn * 32 + l15) * 128;
  const int ck0 = ((0 + g) ^ (l15 & 7)) * 16;
  const int ck1 = ((4 + g) ^ (l15 & 7)) * 16;
  auto RDA = [&](int buf, int mh) {
#pragma unroll
    for (int mi = 0; mi < 4; ++mi) {
      const char* base = sm + (buf * 4 + mh) * 16384 + rdA + mi * 2048;
      ar[mi][0] = *(const bf16x8*)(base + ck0);
      ar[mi][1] = *(const bf16x8*)(base + ck1);
    }
  };
  auto RDB = [&](int buf, int nh) {
#pragma unroll
    for (int ni = 0; ni < 2; ++ni) {
      const char* base = sm + (buf * 4 + 2 + nh) * 16384 + rdB + ni * 2048;
      br[ni][0] = *(const bf16x8*)(base + ck0);
      br[ni][1] = *(const bf16x8*)(base + ck1);
    }
  };

  f32x4 acc[8][4] = {};

  // ---- prologue: tile0 {A0,B0,B1,A1}, tile1 {A0,B1}; drain to last 4 ----
  STA(0, 0); STB(0, 0); STB(1, 0); STA(1, 0);
  STA(0, 1); STB(1, 1);
  VMC4;
  __builtin_amdgcn_s_barrier();

  for (int t = 0; t < NT; t += 2) {
    const bool g2 = (t + 2 < NT), g3 = (t + 3 < NT);
    // p0: tile t quad(0,0) | stage B0(t+1)
    RDA(0, 0); RDB(0, 0); STB(0, t + 1);
    BAR1; mfma_quad<0, 0>(acc, ar, br); BAR2;
    // p1: quad(0,1) | stage A1(t+1)
    RDB(0, 1); STA(1, t + 1);
    BAR1; mfma_quad<0, 1>(acc, ar, br); BAR2;
    // p2: quad(1,1) | stage A0(t+2)
    RDA(0, 1); if (g2) STA(0, t + 2);
    BAR1; mfma_quad<1, 1>(acc, ar, br); BAR2;
    // p3: quad(1,0) | stage B1(t+2) | vmcnt
    RDB(0, 0); if (g2) STB(1, t + 2);
    if (g2) { VMC4; } else { VMC0; }
    BAR1; mfma_quad<1, 0>(acc, ar, br); BAR2;
    // p4: tile t+1 quad(0,0) | stage B0(t+2)
    RDA(1, 0); RDB(1, 0); if (g2) STB(0, t + 2);
    BAR1; mfma_quad<0, 0>(acc, ar, br); BAR2;
    // p5: quad(0,1) | stage A1(t+2)
    RDB(1, 1); if (g2) STA(1, t + 2);
    BAR1; mfma_quad<0, 1>(acc, ar, br); BAR2;
    // p6: quad(1,1) | stage A0(t+3)
    RDA(1, 1); if (g3) STA(0, t + 3);
    BAR1; mfma_quad<1, 1>(acc, ar, br); BAR2;
    // p7: quad(1,0) | stage B1(t+3) | vmcnt
    RDB(1, 0); if (g3) STB(1, t + 3);
    VMC4;
    BAR1; mfma_quad<1, 0>(acc, ar, br); BAR2;
  }

  // ---- epilogue: row=(lane>>4)*4+reg, col=lane&15 per 16x16 frag ----
#pragma unroll
  for (int mf = 0; mf < 8; ++mf)
#pragma unroll
    for (int nf = 0; nf < 4; ++nf) {
      const int row = m0 + wm * 128 + mf * 16 + 4 * g;
      const int col = n0 + wn * 64 + nf * 16 + l15;
      float bv = 0.f;
      if constexpr (EPI == 1) bv = bias[col];
#pragma unroll
      for (int r = 0; r < 4; ++r) {
        float v = acc[mf][nf][r];
        if constexpr (EPI == 1) v = gelu_f(v + bv);
        C[(size_t)(row + r) * N + col] = (bf16)v;
      }
    }
}

// ---------------- generic bf16 GEMM, Bt is (N,K) row-major (128^2 m97) --------
// EPI 2: +bias,+resid, f32 | 3: +resid, f32
template <int EPI>
__global__ __launch_bounds__(256) void gemm_bt(const bf16* __restrict__ A,
                                               const bf16* __restrict__ Bt,
                                               void* __restrict__ Cv,
                                               const float* __restrict__ bias,
                                               const float* __restrict__ resid,
                                               int N, int K) {
  __shared__ bf16 As[128 * 32];
  __shared__ bf16 Bs[128 * 32];
  const int tid = threadIdx.x;
  const int lane = tid & 63, w = tid >> 6;
  const int wr = w >> 1, wc = w & 1;
  const int l15 = lane & 15, g = lane >> 4;
  const int m0 = blockIdx.y * 128, n0 = blockIdx.x * 128;
  f32x4 acc[4][4] = {};
  const int rr = tid >> 2, kc = tid & 3;
  const bf16* Ap0 = A + (size_t)(m0 + rr) * K + kc * 8;
  const bf16* Ap1 = A + (size_t)(m0 + 64 + rr) * K + kc * 8;
  const bf16* Bp0 = Bt + (size_t)(n0 + rr) * K + kc * 8;
  const bf16* Bp1 = Bt + (size_t)(n0 + 64 + rr) * K + kc * 8;
  bf16* As0 = As + tid * 8;
  bf16* As1 = As + 2048 + tid * 8;
  bf16* Bs0 = Bs + tid * 8;
  bf16* Bs1 = Bs + 2048 + tid * 8;

  for (int kt = 0; kt < K; kt += 32) {
    gll16(Ap0 + kt, As0);
    gll16(Ap1 + kt, As1);
    gll16(Bp0 + kt, Bs0);
    gll16(Bp1 + kt, Bs1);
    __syncthreads();
    bf16x8 af[4], bv[4];
#pragma unroll
    for (int i = 0; i < 4; ++i)
      af[i] = *(const bf16x8*)&As[(wr * 64 + i * 16 + l15) * 32 + 8 * g];
#pragma unroll
    for (int i = 0; i < 4; ++i)
      bv[i] = *(const bf16x8*)&Bs[(wc * 64 + i * 16 + l15) * 32 + 8 * g];
#pragma unroll
    for (int mi = 0; mi < 4; ++mi)
#pragma unroll
      for (int ni = 0; ni < 4; ++ni)
        acc[mi][ni] = __builtin_amdgcn_mfma_f32_16x16x32_bf16(af[mi], bv[ni], acc[mi][ni], 0, 0, 0);
    __syncthreads();
  }
#pragma unroll
  for (int mi = 0; mi < 4; ++mi) {
#pragma unroll
    for (int ni = 0; ni < 4; ++ni) {
      const int row = m0 + wr * 64 + mi * 16 + 4 * g;
      const int col = n0 + wc * 64 + ni * 16 + l15;
      float bvv = 0.f;
      if constexpr (EPI == 2) bvv = bias[col];
#pragma unroll
      for (int r = 0; r < 4; ++r) {
        float v = acc[mi][ni][r] + bvv;
        v += resid[(size_t)(row + r) * N + col];
        ((float*)Cv)[(size_t)(row + r) * N + col] = v;
      }
    }
  }
}

// ---------------- V transpose: fused-QKV (stride 1536) -> (B,H,dh,S) ----------
__global__ __launch_bounds__(256) void vtrans(const bf16* __restrict__ V,
                                              bf16* __restrict__ Vt) {
  const int st = blockIdx.x, h = blockIdx.y, b = blockIdx.z;
  __shared__ bf16 tile[64 * 68];
  const int t = threadIdx.x;
#pragma unroll
  for (int i = 0; i < 16; ++i) {
    int lin = i * 256 + t, s = lin >> 6, d = lin & 63;
    tile[s * 68 + d] = V[(size_t)(b * SEQL + st * 64 + s) * QKVS + h * 64 + d];
  }
  __syncthreads();
#pragma unroll
  for (int i = 0; i < 16; ++i) {
    int lin = i * 256 + t, d = lin >> 6, s = lin & 63;
    Vt[(size_t)((b * 8 + h) * 64 + d) * SEQL + st * 64 + s] = tile[s * 68 + d];
  }
}

// ---------------- local attention (Q,K from fused buffer, stride 1536) --------
template <bool FIRST>
__global__ __launch_bounds__(512) void attn_kernel(const bf16* __restrict__ Qb,
                                                   const bf16* __restrict__ Kb,
                                                   const bf16* __restrict__ Vt,
                                                   bf16* __restrict__ O) {
  constexpr int NF = FIRST ? 8 : 16;   // key fragments of 16
  constexpr int KC = FIRST ? 4 : 8;    // key chunks of 32
  const int n = FIRST ? 0 : (blockIdx.x + 1);
  const int h = blockIdx.y, b = blockIdx.z;
  const int tid = threadIdx.x, w = tid >> 6, lane = tid & 63;
  const int l15 = lane & 15, g = lane >> 4;
  __shared__ bf16 P[8][16][256];  // 64 KB
  const int keybase = FIRST ? 0 : (n - 1) * 128;
  const int qbase = n * 128;
  const bf16* qrow = Qb + (size_t)(b * SEQL + qbase + w * 16 + l15) * QKVS + h * 64;
  bf16x8 qf0 = *(const bf16x8*)(qrow + 8 * g);
  bf16x8 qf1 = *(const bf16x8*)(qrow + 32 + 8 * g);
  f32x4 S[NF];
#pragma unroll
  for (int nf = 0; nf < NF; ++nf) S[nf] = f32x4{0.f, 0.f, 0.f, 0.f};
#pragma unroll
  for (int nf = 0; nf < NF; ++nf) {
    const bf16* krow = Kb + (size_t)(b * SEQL + keybase + nf * 16 + l15) * QKVS + h * 64;
    bf16x8 kf0 = *(const bf16x8*)(krow + 8 * g);
    bf16x8 kf1 = *(const bf16x8*)(krow + 32 + 8 * g);
    S[nf] = __builtin_amdgcn_mfma_f32_16x16x32_bf16(qf0, kf0, S[nf], 0, 0, 0);
    S[nf] = __builtin_amdgcn_mfma_f32_16x16x32_bf16(qf1, kf1, S[nf], 0, 0, 0);
  }
#pragma unroll
  for (int rr = 0; rr < 4; ++rr) {
    const int qloc = w * 16 + 4 * g + rr;
    float mx = -3.0e38f;
#pragma unroll
    for (int nf = 0; nf < NF; ++nf) {
      const int key = nf * 16 + l15;
      const bool valid = FIRST ? (key <= qloc) : (key <= qloc + 128);
      float v = valid ? S[nf][rr] * 0.125f : -1.0e9f;
      S[nf][rr] = v;
      mx = fmaxf(mx, v);
    }
    mx = fmaxf(mx, __shfl_xor(mx, 1));
    mx = fmaxf(mx, __shfl_xor(mx, 2));
    mx = fmaxf(mx, __shfl_xor(mx, 4));
    mx = fmaxf(mx, __shfl_xor(mx, 8));
    float sden = 0.f;
#pragma unroll
    for (int nf = 0; nf < NF; ++nf) {
      float e = expf(S[nf][rr] - mx);
      S[nf][rr] = e;
      sden += e;
    }
    sden += __shfl_xor(sden, 1);
    sden += __shfl_xor(sden, 2);
    sden += __shfl_xor(sden, 4);
    sden += __shfl_xor(sden, 8);
    const float rcp = 1.0f / sden;
#pragma unroll
    for (int nf = 0; nf < NF; ++nf)
      P[w][4 * g + rr][nf * 16 + l15] = (bf16)(S[nf][rr] * rcp);
  }
  f32x4 Oacc[4];
#pragma unroll
  for (int i = 0; i < 4; ++i) Oacc[i] = f32x4{0.f, 0.f, 0.f, 0.f};
#pragma unroll
  for (int kc = 0; kc < KC; ++kc) {
    bf16x8 pa = *(const bf16x8*)&P[w][l15][kc * 32 + 8 * g];
#pragma unroll
    for (int nf = 0; nf < 4; ++nf) {
      const bf16* vrow = Vt + (size_t)((b * 8 + h) * 64 + nf * 16 + l15) * SEQL +
                         keybase + kc * 32 + 8 * g;
      bf16x8 vf = *(const bf16x8*)vrow;
      Oacc[nf] = __builtin_amdgcn_mfma_f32_16x16x32_bf16(pa, vf, Oacc[nf], 0, 0, 0);
    }
  }
#pragma unroll
  for (int nf = 0; nf < 4; ++nf)
#pragma unroll
    for (int rr = 0; rr < 4; ++rr)
      O[(size_t)(b * SEQL + qbase + w * 16 + 4 * g + rr) * HIDD + h * 64 + nf * 16 + l15] =
          (bf16)Oacc[nf][rr];
}

// ---------------- LayerNorm over 512, writes f32 + bf16 ----------------
__global__ __launch_bounds__(256) void ln_kernel(const float* __restrict__ Z,
                                                 const float* __restrict__ Gm,
                                                 const float* __restrict__ Bv,
                                                 float* __restrict__ Hf,
                                                 bf16* __restrict__ Hb) {
  const int row = blockIdx.x * 4 + (threadIdx.x >> 6);
  const int lane = threadIdx.x & 63;
  const float* zr = Z + (size_t)row * HIDD + lane * 8;
  f32x4 v0 = *(const f32x4*)zr;
  f32x4 v1 = *(const f32x4*)(zr + 4);
  float s = v0[0] + v0[1] + v0[2] + v0[3] + v1[0] + v1[1] + v1[2] + v1[3];
#pragma unroll
  for (int m = 1; m < 64; m <<= 1) s += __shfl_xor(s, m);
  const float mean = s * (1.0f / 512.0f);
  float q = 0.f;
#pragma unroll
  for (int j = 0; j < 4; ++j) {
    float d0 = v0[j] - mean, d1 = v1[j] - mean;
    q += d0 * d0 + d1 * d1;
  }
#pragma unroll
  for (int m = 1; m < 64; m <<= 1) q += __shfl_xor(q, m);
  const float rs = rsqrtf(q * (1.0f / 512.0f) + 1e-6f);
  const int dbase = lane * 8;
  f32x4 g0 = *(const f32x4*)(Gm + dbase), g1 = *(const f32x4*)(Gm + dbase + 4);
  f32x4 b0 = *(const f32x4*)(Bv + dbase), b1 = *(const f32x4*)(Bv + dbase + 4);
  f32x4 o0, o1;
  bf16x8 ob;
#pragma unroll
  for (int j = 0; j < 4; ++j) {
    o0[j] = (v0[j] - mean) * rs * g0[j] + b0[j];
    o1[j] = (v1[j] - mean) * rs * g1[j] + b1[j];
    ob[j] = (bf16)o0[j];
    ob[j + 4] = (bf16)o1[j];
  }
  *(f32x4*)(Hf + (size_t)row * HIDD + dbase) = o0;
  *(f32x4*)(Hf + (size_t)row * HIDD + dbase + 4) = o1;
  *(bf16x8*)(Hb + (size_t)row * HIDD + dbase) = ob;
}

// ---------------- final projection ----------------
__global__ __launch_bounds__(256) void proj_partial(const float* __restrict__ Hf,
                                                    const float* __restrict__ W,
                                                    float* __restrict__ part) {
  const int kc = blockIdx.x;  // 0..767
  const int t = threadIdx.x;
  __shared__ float Al[512 * 20];
  const size_t k0 = (size_t)kc * 512;
#pragma unroll
  for (int i = 0; i < 32; ++i) {
    int lin = i * 256 + t, m = lin >> 9, kk = lin & 511;
    Al[kk * 20 + m] = Hf[(size_t)m * 393216 + k0 + kk];
  }
  __syncthreads();
  float acc[16] = {};
  for (int kk = 0; kk < 512; ++kk) {
    const float wv = W[(k0 + kk) * 256 + t];
    const f32x4* a = (const f32x4*)&Al[kk * 20];
#pragma unroll
    for (int j = 0; j < 4; ++j) {
      f32x4 av = a[j];
      acc[j * 4 + 0] += av[0] * wv;
      acc[j * 4 + 1] += av[1] * wv;
      acc[j * 4 + 2] += av[2] * wv;
      acc[j * 4 + 3] += av[3] * wv;
    }
  }
#pragma unroll
  for (int m = 0; m < 16; ++m) part[(size_t)kc * 4096 + m * 256 + t] = acc[m];
}

__global__ __launch_bounds__(256) void proj_reduce1(const float* __restrict__ part,
                                                    float* __restrict__ part2) {
  const int i = blockIdx.x * 256 + threadIdx.x;
  const int cb = blockIdx.y;
  float s = 0.f;
  for (int c = cb * 64; c < cb * 64 + 64; ++c) s += part[(size_t)c * 4096 + i];
  part2[(size_t)cb * 4096 + i] = s;
}

__global__ __launch_bounds__(256) void proj_final(const float* __restrict__ part2,
                                                  const float* __restrict__ g,
                                                  const float* __restrict__ bt,
                                                  float* __restrict__ out) {
  const int row = blockIdx.x, t = threadIdx.x;
  float v = 0.f;
#pragma unroll
  for (int c = 0; c < 12; ++c) v += part2[(size_t)c * 4096 + row * 256 + t];
  const float x = gelu_f(v);
  __shared__ float red[256];
  red[t] = x;
  __syncthreads();
  for (int off = 128; off > 0; off >>= 1) {
    if (t < off) red[t] += red[t + off];
    __syncthreads();
  }
  const float mean = red[0] * (1.0f / 256.0f);
  __syncthreads();
  const float dx = x - mean;
  red[t] = dx * dx;
  __syncthreads();
  for (int off = 128; off > 0; off >>= 1) {
    if (t < off) red[t] += red[t + off];
    __syncthreads();
  }
  const float var = red[0] * (1.0f / 256.0f);
  const float rs = rsqrtf(var + 1e-6f);
  out[row * 256 + t] = dx * rs * g[t] + bt[t];
}

extern "C" void kernel_launch(void* const* d_in, const int* in_sizes, int n_in,
                              void* d_out, int out_size, void* d_ws, size_t ws_size,
                              hipStream_t stream) {
  const float* X = (const float*)d_in[0];
  const float* ET = (const float*)d_in[1];
  const float* Wq = (const float*)d_in[2];
  const float* Wk = (const float*)d_in[3];
  const float* Wv = (const float*)d_in[4];
  const float* Wo = (const float*)d_in[5];
  const float* ln1g = (const float*)d_in[6];
  const float* ln1b = (const float*)d_in[7];
  const float* W1 = (const float*)d_in[8];
  const float* b1 = (const float*)d_in[9];
  const float* W2 = (const float*)d_in[10];
  const float* b2 = (const float*)d_in[11];
  const float* ln2g = (const float*)d_in[12];
  const float* ln2b = (const float*)d_in[13];
  const float* PW = (const float*)d_in[14];
  const float* og = (const float*)d_in[15];
  const float* obv = (const float*)d_in[16];
  float* out = (float*)d_out;

  hipFuncSetAttribute((const void*)gemm8p<0>, hipFuncAttributeMaxDynamicSharedMemorySize, 131072);
  hipFuncSetAttribute((const void*)gemm8p<1>, hipFuncAttributeMaxDynamicSharedMemorySize, 131072);

  char* p = (char*)d_ws;
  auto alloc = [&](size_t bytes) {
    char* r = p;
    p += (bytes + 255) & ~(size_t)255;
    return r;
  };
  bf16* Wqkvt = (bf16*)alloc((size_t)NLAYER * QKVS * 512 * 2);
  bf16* Wot = (bf16*)alloc((size_t)NLAYER * 512 * 512 * 2);
  bf16* W1t = (bf16*)alloc((size_t)NLAYER * 512 * 2048 * 2);
  bf16* W2t = (bf16*)alloc((size_t)NLAYER * 512 * 2048 * 2);
  float* hF = (float*)alloc((size_t)MROWS * HIDD * 4);
  bf16* hB = (bf16*)alloc((size_t)MROWS * HIDD * 2);
  float* zF = (float*)alloc((size_t)MROWS * HIDD * 4);
  bf16* qkvB = (bf16*)alloc((size_t)MROWS * QKVS * 2);
  bf16* vT = (bf16*)alloc((size_t)MROWS * HIDD * 2);
  bf16* aO = (bf16*)alloc((size_t)MROWS * HIDD * 2);
  bf16* mid = (bf16*)alloc((size_t)MROWS * 2048 * 2);
  float* part = (float*)alloc((size_t)768 * 4096 * 4);
  float* part2 = (float*)alloc((size_t)12 * 4096 * 4);
  (void)ws_size; (void)n_in; (void)in_sizes; (void)out_size;

  // weight conversion (per call; cheap). QKV fused: rows [0,512)=Q, [512,1024)=K, [1024,1536)=V
  wtrans<<<dim3(16, 16, 6), 256, 0, stream>>>(Wq, Wqkvt, 512, 512, (size_t)QKVS * 512);
  wtrans<<<dim3(16, 16, 6), 256, 0, stream>>>(Wk, Wqkvt + 512 * 512, 512, 512, (size_t)QKVS * 512);
  wtrans<<<dim3(16, 16, 6), 256, 0, stream>>>(Wv, Wqkvt + 1024 * 512, 512, 512, (size_t)QKVS * 512);
  wtrans<<<dim3(16, 16, 6), 256, 0, stream>>>(Wo, Wot, 512, 512, (size_t)512 * 512);
  wtrans<<<dim3(64, 16, 6), 256, 0, stream>>>(W1, W1t, 512, 2048, (size_t)512 * 2048);
  wtrans<<<dim3(16, 64, 6), 256, 0, stream>>>(W2, W2t, 2048, 512, (size_t)512 * 2048);

  embed_kernel<<<MROWS, 128, 0, stream>>>(X, ET, hF, hB);

  for (int i = 0; i < NLAYER; ++i) {
    const size_t wo512 = (size_t)i * 512 * 512;
    const size_t wo2048 = (size_t)i * 512 * 2048;
    gemm8p<0><<<dim3(6, 48), 512, 131072, stream>>>(hB, Wqkvt + (size_t)i * QKVS * 512, qkvB,
                                                    nullptr, QKVS, 512);
    vtrans<<<dim3(12, 8, 16), 256, 0, stream>>>(qkvB + 1024, vT);
    attn_kernel<true><<<dim3(1, 8, 16), 512, 0, stream>>>(qkvB, qkvB + 512, vT, aO);
    attn_kernel<false><<<dim3(5, 8, 16), 512, 0, stream>>>(qkvB, qkvB + 512, vT, aO);
    gemm_bt<3><<<dim3(4, 96), 256, 0, stream>>>(aO, Wot + wo512, zF, nullptr, hF, 512, 512);
    ln_kernel<<<MROWS / 4, 256, 0, stream>>>(zF, ln1g + i * 512, ln1b + i * 512, hF, hB);
    gemm8p<1><<<dim3(8, 48), 512, 131072, stream>>>(hB, W1t + wo2048, mid, b1 + i * 2048, 2048, 512);
    gemm_bt<2><<<dim3(4, 96), 256, 0, stream>>>(mid, W2t + wo2048, zF, b2 + i * 512, hF, 512, 2048);
    ln_kernel<<<MROWS / 4, 256, 0, stream>>>(zF, ln2g + i * 512, ln2b + i * 512, hF, hB);
  }

  proj_partial<<<768, 256, 0, stream>>>(hF, PW, part);
  proj_reduce1<<<dim3(16, 12), 256, 0, stream>>>(part, part2);
  proj_final<<<16, 256, 0, stream>>>(part2, og, obv, out);
}